// Round 1
// baseline (806.257 us; speedup 1.0000x reference)
//
#include <hip/hip_runtime.h>

#define B 8
#define P 2048
#define C 1024
#define K 3
#define T 512  // threads per NMS block

// ---------------------------------------------------------------------------
// Kernel A: per-scene greedy NMS (sorted-scan formulation) + small outputs
// One block per scene. Greedy argmax NMS == scan in (score desc, idx asc)
// order keeping j iff no earlier-kept point suppresses j. Same-class
// requirement makes keeper radius == candidate radius.
// ---------------------------------------------------------------------------
__global__ __launch_bounds__(T) void nms_kernel(
    const float* __restrict__ centers,
    const float* __restrict__ cls_preds,
    const float* __restrict__ class_radius,
    float* __restrict__ out_centers,
    float* __restrict__ out_cls,
    float* __restrict__ out_keep)
{
    __shared__ float4 s_c[P];            // sorted centers, w = label bits
    __shared__ float s_key[P];           // scores (sort key)
    __shared__ int s_val[P];             // original indices (sort payload)
    __shared__ unsigned char s_lab[P];   // labels by ORIGINAL index
    __shared__ unsigned char s_removed[P];
    __shared__ unsigned char s_keep[P];
    __shared__ int s_list[64];           // kept points of current chunk
    __shared__ int s_cnt;
    __shared__ float s_rad[K];

    const int b = blockIdx.x;
    const int tid = threadIdx.x;

    if (tid < K) s_rad[tid] = class_radius[tid];

    // ---- scores + labels (argmax with first-index-wins via strict >) ----
    const float* clsb = cls_preds + (size_t)b * P * K;
    for (int p = tid; p < P; p += T) {
        float s0 = clsb[p * 3 + 0], s1 = clsb[p * 3 + 1], s2 = clsb[p * 3 + 2];
        float sc = s0; int lb = 0;
        if (s1 > sc) { sc = s1; lb = 1; }
        if (s2 > sc) { sc = s2; lb = 2; }
        s_key[p] = sc;
        s_val[p] = p;
        s_lab[p] = (unsigned char)lb;
    }
    __syncthreads();

    // ---- bitonic sort: descending score, ties -> smaller original index ----
    for (int k = 2; k <= P; k <<= 1) {
        for (int j = k >> 1; j > 0; j >>= 1) {
            for (int i = tid; i < P; i += T) {
                int ixj = i ^ j;
                if (ixj > i) {
                    float si = s_key[i], sj = s_key[ixj];
                    int vi = s_val[i], vj = s_val[ixj];
                    // "before": element at ixj should precede element at i
                    bool before = (sj > si) || (sj == si && vj < vi);
                    bool dirUp = ((i & k) == 0);
                    if (before == dirUp) {
                        s_key[i] = sj; s_key[ixj] = si;
                        s_val[i] = vj; s_val[ixj] = vi;
                    }
                }
            }
            __syncthreads();
        }
    }

    // ---- gather centers/labels into sorted order ----
    const float* cenb = centers + (size_t)b * P * 3;
    for (int pos = tid; pos < P; pos += T) {
        int orig = s_val[pos];
        float4 c;
        c.x = cenb[orig * 3 + 0];
        c.y = cenb[orig * 3 + 1];
        c.z = cenb[orig * 3 + 2];
        c.w = __int_as_float((int)s_lab[orig]);
        s_c[pos] = c;
        s_removed[pos] = 0;
        s_keep[pos] = 0;
    }
    __syncthreads();

    // ---- chunked greedy scan: 32 chunks of 64 points ----
    for (int g = 0; g < P / 64; ++g) {
        const int base = g * 64;
        if (tid < 64) {   // wave 0 resolves the chunk serially via ballots
            const int p = base + tid;
            float4 cL = s_c[p];
            int labL = __float_as_int(cL.w);
            float rL = s_rad[labL];
            float rL2 = rL * rL;
            // myrow bit k: chunk point k suppresses me (lane tid)
            unsigned long long myrow = 0ull;
            for (int k2 = 0; k2 < 64; ++k2) {
                float4 ck = s_c[base + k2];   // broadcast LDS read
                if (__float_as_int(ck.w) == labL) {
                    float dx = cL.x - ck.x, dy = cL.y - ck.y, dz = cL.z - ck.z;
                    float ss = dx * dx + dy * dy + dz * dz;
                    if (ss < rL2) myrow |= (1ull << k2);
                }
            }
            unsigned long long rem = __ballot(s_removed[p] != 0);  // uniform
            unsigned long long keepmask = 0ull;
            for (int k2 = 0; k2 < 64; ++k2) {
                if (!((rem >> k2) & 1ull)) {          // uniform branch
                    keepmask |= (1ull << k2);
                    rem |= __ballot((int)((myrow >> k2) & 1ull));
                }
            }
            s_keep[p] = (unsigned char)((keepmask >> tid) & 1ull);
            if ((keepmask >> tid) & 1ull) {
                int slot = (int)__popcll(keepmask & ((1ull << tid) - 1ull));
                s_list[slot] = p;
            }
            if (tid == 0) s_cnt = (int)__popcll(keepmask);
        }
        __syncthreads();
        const int cnt = s_cnt;
        if (cnt > 0) {
            // all threads: suppress later points vs this chunk's kept points
            for (int jp = base + 64 + tid; jp < P; jp += T) {
                if (s_removed[jp]) continue;
                float4 cj = s_c[jp];
                int labj = __float_as_int(cj.w);
                float rj = s_rad[labj];           // keeper radius == mine (same class)
                float rj2 = rj * rj;
                for (int t = 0; t < cnt; ++t) {
                    float4 ck = s_c[s_list[t]];   // broadcast LDS read
                    if (__float_as_int(ck.w) == labj) {
                        float dx = cj.x - ck.x, dy = cj.y - ck.y, dz = cj.z - ck.z;
                        if (dx * dx + dy * dy + dz * dz < rj2) {
                            s_removed[jp] = 1;
                            break;
                        }
                    }
                }
            }
        }
        __syncthreads();
    }

    // ---- write keep, centers*m, cls_preds*m (scatter by original index) ----
    for (int pos = tid; pos < P; pos += T) {
        int orig = s_val[pos];
        float m = s_keep[pos] ? 1.0f : 0.0f;
        size_t rb = (size_t)b * P + orig;
        out_keep[rb] = m;
        float4 c = s_c[pos];
        out_centers[rb * 3 + 0] = c.x * m;
        out_centers[rb * 3 + 1] = c.y * m;
        out_centers[rb * 3 + 2] = c.z * m;
        out_cls[rb * 3 + 0] = clsb[orig * 3 + 0] * m;
        out_cls[rb * 3 + 1] = clsb[orig * 3 + 1] * m;
        out_cls[rb * 3 + 2] = clsb[orig * 3 + 2] * m;
    }
}

// ---------------------------------------------------------------------------
// Kernel B: features * mask — pure HBM streaming, one row per block,
// one float4 per thread (256 * 4 = 1024 = C).
// ---------------------------------------------------------------------------
__global__ __launch_bounds__(256) void mask_feat_kernel(
    const float* __restrict__ feat,
    const float* __restrict__ keepf,
    float* __restrict__ outf)
{
    const int row = blockIdx.x;          // 0 .. B*P-1
    const float m = keepf[row];
    const float4* fin = (const float4*)(feat + (size_t)row * C);
    float4* fo = (float4*)(outf + (size_t)row * C);
    float4 v = fin[threadIdx.x];
    v.x *= m; v.y *= m; v.z *= m; v.w *= m;
    fo[threadIdx.x] = v;
}

extern "C" void kernel_launch(void* const* d_in, const int* in_sizes, int n_in,
                              void* d_out, int out_size, void* d_ws, size_t ws_size,
                              hipStream_t stream) {
    const float* centers      = (const float*)d_in[0];
    const float* features     = (const float*)d_in[1];
    const float* cls_preds    = (const float*)d_in[2];
    const float* class_radius = (const float*)d_in[3];

    float* out = (float*)d_out;
    // tuple layout, flat concat in return order:
    float* out_centers = out;                                   // B*P*3
    float* out_feat    = out + (size_t)B * P * 3;               // B*P*C
    float* out_cls     = out_feat + (size_t)B * P * C;          // B*P*K
    float* out_keep    = out_cls + (size_t)B * P * K;           // B*P

    hipLaunchKernelGGL(nms_kernel, dim3(B), dim3(T), 0, stream,
                       centers, cls_preds, class_radius,
                       out_centers, out_cls, out_keep);
    hipLaunchKernelGGL(mask_feat_kernel, dim3(B * P), dim3(256), 0, stream,
                       features, out_keep, out_feat);
}

// Round 2
// 301.175 us; speedup vs baseline: 2.6770x; 2.6770x over previous
//
#include <hip/hip_runtime.h>

#define B 8
#define P 2048
#define C 1024
#define K 3
#define T 1024          // 16 waves
#define NCHUNK (P / 64)

// ---------------------------------------------------------------------------
// Kernel A: per-scene greedy NMS (sorted-scan formulation) + small outputs.
// Greedy argmax NMS == scan in (score desc, idx asc) order keeping j iff no
// earlier-kept point suppresses j. Same-class requirement => keeper radius ==
// candidate radius (condition symmetric in the pair).
//
// Round-2 structure: chunk-of-64 processing.
//   - 64x64 suppression rows built by ALL 16 waves (4 rows/wave, one ballot
//     each) -- independent, pipelined LDS reads.
//   - wave 0 resolves the chunk with a 64-step uniform ballot scan, then
//     compacts kept centers into dense per-class LDS lists (removes the
//     dependent s_list -> s_c indirection that cost ~250 serial cyc/check).
//   - all 1024 threads suppress later points against the dense keeper lists
//     with unrolled, break-free (per-4 early-out) loops -> loads pipeline.
//   - rows for chunk g+1 are built during chunk g's suppress phase (they
//     don't depend on s_removed) -> 2 barriers per chunk.
// ---------------------------------------------------------------------------
__global__ __launch_bounds__(T) void nms_kernel(
    const float* __restrict__ centers,
    const float* __restrict__ cls_preds,
    const float* __restrict__ class_radius,
    float* __restrict__ out_centers,
    float* __restrict__ out_cls,
    float* __restrict__ out_keep)
{
    __shared__ float4 s_c[P];                 // sorted centers, w = label bits
    __shared__ float s_key[P];                // scores (sort key)
    __shared__ int s_val[P];                  // (orig_idx << 2) | label
    __shared__ unsigned char s_removed[P];
    __shared__ unsigned char s_keep[P];
    __shared__ unsigned long long s_rows[64]; // row r: bit l = l suppresses r
    __shared__ float4 s_kc[K][64];            // current chunk keepers, by class
    __shared__ int s_kcnt[K];
    __shared__ float s_rad2[K];

    const int b = blockIdx.x;
    const int tid = threadIdx.x;
    const int wave = tid >> 6;
    const int lane = tid & 63;

    if (tid < K) { float r = class_radius[tid]; s_rad2[tid] = r * r; }

    const float* clsb = cls_preds + (size_t)b * P * K;
    const float* cenb = centers + (size_t)b * P * 3;

    // ---- scores + labels (argmax, first-index-wins via strict >) ----
    for (int p = tid; p < P; p += T) {
        float s0 = clsb[p * 3 + 0], s1 = clsb[p * 3 + 1], s2 = clsb[p * 3 + 2];
        float sc = s0; int lb = 0;
        if (s1 > sc) { sc = s1; lb = 1; }
        if (s2 > sc) { sc = s2; lb = 2; }
        s_key[p] = sc;
        s_val[p] = (p << 2) | lb;   // tie-order on packed == order on p
    }
    __syncthreads();

    // ---- bitonic sort: descending score, ties -> smaller original index ----
    for (int k = 2; k <= P; k <<= 1) {
        for (int j = k >> 1; j > 0; j >>= 1) {
            for (int i = tid; i < P; i += T) {
                int ixj = i ^ j;
                if (ixj > i) {
                    float si = s_key[i], sj = s_key[ixj];
                    int vi = s_val[i], vj = s_val[ixj];
                    bool before = (sj > si) || (sj == si && vj < vi);
                    bool dirUp = ((i & k) == 0);
                    if (before == dirUp) {
                        s_key[i] = sj; s_key[ixj] = si;
                        s_val[i] = vj; s_val[ixj] = vi;
                    }
                }
            }
            __syncthreads();
        }
    }

    // ---- gather centers/labels into sorted order ----
    for (int pos = tid; pos < P; pos += T) {
        int v = s_val[pos];
        int orig = v >> 2;
        float4 c;
        c.x = cenb[orig * 3 + 0];
        c.y = cenb[orig * 3 + 1];
        c.z = cenb[orig * 3 + 2];
        c.w = __int_as_float(v & 3);
        s_c[pos] = c;
        s_removed[pos] = 0;
        s_keep[pos] = 0;
    }
    __syncthreads();

    // distributed 64x64 row build: 4 rows per wave, one ballot per row
    auto build_rows = [&](int base) {
        float4 cL = s_c[base + lane];
        int labL = __float_as_int(cL.w);
        #pragma unroll
        for (int rr = 0; rr < 4; ++rr) {
            int r = wave * 4 + rr;
            float4 cR = s_c[base + r];               // broadcast read
            int labR = __float_as_int(cR.w);
            float dx = cL.x - cR.x, dy = cL.y - cR.y, dz = cL.z - cR.z;
            float dd = dx * dx + dy * dy + dz * dz;
            bool sup = (labL == labR) && (dd < s_rad2[labR]);
            unsigned long long m = __ballot(sup);
            if (lane == 0) s_rows[r] = m;
        }
    };

    build_rows(0);
    __syncthreads();

    for (int g = 0; g < NCHUNK; ++g) {
        const int base = g * 64;

        // ---- resolve chunk (wave 0): uniform 64-step ballot scan ----
        if (wave == 0) {
            unsigned long long myrow = s_rows[lane];  // who suppresses me
            float4 cL = s_c[base + lane];
            int labL = __float_as_int(cL.w);
            unsigned long long rem = __ballot(s_removed[base + lane] != 0);
            unsigned long long keepmask = 0ull;
            for (int k = 0; k < 64; ++k) {
                if (!((rem >> k) & 1ull)) {           // uniform branch
                    keepmask |= 1ull << k;
                    rem |= 1ull << k;
                    rem |= __ballot((int)((myrow >> k) & 1ull));
                }
            }
            s_keep[base + lane] = (unsigned char)((keepmask >> lane) & 1ull);
            // per-class compaction of kept centers into dense lists
            unsigned long long b0 = __ballot(labL == 0);
            unsigned long long b1 = __ballot(labL == 1);
            unsigned long long b2 = __ballot(labL == 2);
            unsigned long long bc = (labL == 0) ? b0 : ((labL == 1) ? b1 : b2);
            unsigned long long cmask = bc & keepmask;
            if ((keepmask >> lane) & 1ull) {
                int slot = (int)__popcll(cmask & ((1ull << lane) - 1ull));
                s_kc[labL][slot] = cL;
            }
            if (lane < K) {
                unsigned long long bl = (lane == 0) ? b0 : ((lane == 1) ? b1 : b2);
                s_kcnt[lane] = (int)__popcll(bl & keepmask);
            }
        }
        __syncthreads();

        // ---- suppress later points vs dense per-class keeper list ----
        for (int jp = base + 64 + tid; jp < P; jp += T) {
            if (s_removed[jp]) continue;
            float4 cj = s_c[jp];
            int c = __float_as_int(cj.w);
            float r2 = s_rad2[c];
            int cnt = s_kcnt[c];
            bool sup = false;
            int t = 0;
            for (; t + 4 <= cnt; t += 4) {            // break-free inner 4
                float m0 = 1e30f;
                #pragma unroll
                for (int u = 0; u < 4; ++u) {
                    float4 ck = s_kc[c][t + u];       // dense, independent
                    float dx = cj.x - ck.x, dy = cj.y - ck.y, dz = cj.z - ck.z;
                    m0 = fminf(m0, dx * dx + dy * dy + dz * dz);
                }
                if (m0 < r2) { sup = true; break; }
            }
            if (!sup) {
                for (; t < cnt; ++t) {
                    float4 ck = s_kc[c][t];
                    float dx = cj.x - ck.x, dy = cj.y - ck.y, dz = cj.z - ck.z;
                    if (dx * dx + dy * dy + dz * dz < r2) { sup = true; break; }
                }
            }
            if (sup) s_removed[jp] = 1;
        }
        // ---- build rows for next chunk (independent of s_removed) ----
        if (g + 1 < NCHUNK) build_rows((g + 1) * 64);
        __syncthreads();
    }

    // ---- write keep, centers*m, cls_preds*m (scatter by original index) ----
    for (int pos = tid; pos < P; pos += T) {
        int v = s_val[pos];
        int orig = v >> 2;
        float m = s_keep[pos] ? 1.0f : 0.0f;
        size_t rb = (size_t)b * P + orig;
        out_keep[rb] = m;
        float4 c = s_c[pos];
        out_centers[rb * 3 + 0] = c.x * m;
        out_centers[rb * 3 + 1] = c.y * m;
        out_centers[rb * 3 + 2] = c.z * m;
        out_cls[rb * 3 + 0] = clsb[orig * 3 + 0] * m;
        out_cls[rb * 3 + 1] = clsb[orig * 3 + 1] * m;
        out_cls[rb * 3 + 2] = clsb[orig * 3 + 2] * m;
    }
}

// ---------------------------------------------------------------------------
// Kernel B: features * mask — pure HBM streaming, one row per block,
// one float4 per thread (256 * 4 = 1024 = C).
// ---------------------------------------------------------------------------
__global__ __launch_bounds__(256) void mask_feat_kernel(
    const float* __restrict__ feat,
    const float* __restrict__ keepf,
    float* __restrict__ outf)
{
    const int row = blockIdx.x;          // 0 .. B*P-1
    const float m = keepf[row];
    const float4* fin = (const float4*)(feat + (size_t)row * C);
    float4* fo = (float4*)(outf + (size_t)row * C);
    float4 v = fin[threadIdx.x];
    v.x *= m; v.y *= m; v.z *= m; v.w *= m;
    fo[threadIdx.x] = v;
}

extern "C" void kernel_launch(void* const* d_in, const int* in_sizes, int n_in,
                              void* d_out, int out_size, void* d_ws, size_t ws_size,
                              hipStream_t stream) {
    const float* centers      = (const float*)d_in[0];
    const float* features     = (const float*)d_in[1];
    const float* cls_preds    = (const float*)d_in[2];
    const float* class_radius = (const float*)d_in[3];

    float* out = (float*)d_out;
    float* out_centers = out;                                   // B*P*3
    float* out_feat    = out + (size_t)B * P * 3;               // B*P*C
    float* out_cls     = out_feat + (size_t)B * P * C;          // B*P*K
    float* out_keep    = out_cls + (size_t)B * P * K;           // B*P

    hipLaunchKernelGGL(nms_kernel, dim3(B), dim3(T), 0, stream,
                       centers, cls_preds, class_radius,
                       out_centers, out_cls, out_keep);
    hipLaunchKernelGGL(mask_feat_kernel, dim3(B * P), dim3(256), 0, stream,
                       features, out_keep, out_feat);
}